// Round 1
// baseline (520.364 us; speedup 1.0000x reference)
//
#include <hip/hip_runtime.h>

#define T_TOK 1024
#define HD    2048
#define NE    64
#define ID    768
#define TOPK  8

typedef __bf16 bf16x8 __attribute__((ext_vector_type(8)));
typedef float  f32x4  __attribute__((ext_vector_type(4)));

__device__ __forceinline__ void load_lds16(const void* src, void* lds) {
  __builtin_amdgcn_global_load_lds(
      (__attribute__((address_space(1))) const void*)src,
      (__attribute__((address_space(3))) void*)lds, 16, 0, 0);
}

// ---------------------------------------------------------------------------
// Router: fp64 logits -> top-8 -> renormalized weights; build per-expert lists;
// also convert x to bf16 for the expert GEMMs.
// ---------------------------------------------------------------------------
__global__ __launch_bounds__(256) void router_kernel(
    const float* __restrict__ x, const float* __restrict__ rw,
    unsigned short* __restrict__ xb_u, float* __restrict__ tw,
    int* __restrict__ counts, int* __restrict__ lists)
{
  __shared__ float  sx[HD];
  __shared__ double slog[NE];
  const int t = blockIdx.x;
  const int tid = threadIdx.x;
  __bf16* xb = (__bf16*)xb_u;

  for (int i = tid; i < HD; i += 256) {
    float v = x[(size_t)t * HD + i];
    sx[i] = v;
    xb[(size_t)t * HD + i] = (__bf16)v;
  }
  __syncthreads();

  // 4 lanes per expert, fp64 accumulate
  const int e = tid >> 2, p = tid & 3;
  const float* rwrow = rw + (size_t)e * HD;
  double acc = 0.0;
  for (int k = p; k < HD; k += 4)
    acc += (double)sx[k] * (double)rwrow[k];
  acc += __shfl_xor(acc, 1, 64);
  acc += __shfl_xor(acc, 2, 64);
  if (p == 0) slog[e] = acc;
  __syncthreads();

  if (tid < 64) {
    double v = slog[tid];
    double selv = -1e300; int seli = 0; double gmax = 0.0;
    #pragma unroll
    for (int k = 0; k < TOPK; ++k) {
      double bv = v; int bi = tid;
      #pragma unroll
      for (int off = 32; off >= 1; off >>= 1) {
        double ov = __shfl_xor(bv, off, 64);
        int    oi = __shfl_xor(bi, off, 64);
        if (ov > bv || (ov == bv && oi < bi)) { bv = ov; bi = oi; }
      }
      if (k == 0) gmax = bv;
      if (tid == k) { selv = bv; seli = bi; }
      if (tid == bi) v = -1e300;
    }
    // weights: softmax over selected 8 (full-softmax normalizer cancels in renorm)
    double e_ = (tid < TOPK) ? exp(selv - gmax) : 0.0;
    double s = e_;
    #pragma unroll
    for (int off = 32; off >= 1; off >>= 1) s += __shfl_xor(s, off, 64);
    if (tid < TOPK) {
      int slot = t * TOPK + tid;          // assignment slot = token*8 + k
      tw[slot] = (float)(e_ / s);
      int pos = atomicAdd(&counts[seli], 1);
      lists[seli * T_TOK + pos] = slot;
    }
  }
}

// ---------------------------------------------------------------------------
// GEMM1: per expert, X_e[M x 2048] @ {gate,up}^T[768 x 2048] -> silu(g)*u
// BM=256 (one tile covers n_e), BN=64, BK=64, 4 waves, 16x16x32 bf16 MFMA.
// A staged via global_load_lds (pre-swizzled source), weights reg-staged
// fp32->bf16 with the same XOR-(row&7) 16B-slot swizzle.
// ---------------------------------------------------------------------------
__global__ __launch_bounds__(256, 2) void gemm1_kernel(
    const unsigned short* __restrict__ xb_u,
    const float* __restrict__ gw, const float* __restrict__ uw,
    const int* __restrict__ counts, const int* __restrict__ lists,
    const unsigned short* __restrict__ zp_u,
    unsigned short* __restrict__ hb_u)
{
  __shared__ __bf16 sA[256 * 64];
  __shared__ __bf16 sG[64 * 64];
  __shared__ __bf16 sU[64 * 64];
  __shared__ int    sSlot[256];

  const __bf16* xb = (const __bf16*)xb_u;
  const __bf16* zp = (const __bf16*)zp_u;
  __bf16* hb = (__bf16*)hb_u;

  const int e   = blockIdx.y;
  const int n0  = blockIdx.x * 64;
  const int tid = threadIdx.x;
  const int wid = tid >> 6;
  const int lane = tid & 63;
  const int n_e = counts[e];

  for (int m0 = 0; m0 < n_e; m0 += 256) {
    sSlot[tid] = (m0 + tid < n_e) ? lists[e * T_TOK + m0 + tid] : -1;
    __syncthreads();

    // per-lane A source base (pre-swizzled so linear LDS dest == swizzled layout)
    const __bf16* abase[8];
    #pragma unroll
    for (int i = 0; i < 8; ++i) {
      int r = wid * 64 + i * 8 + (lane >> 3);
      int slot = sSlot[r];
      int sl = (lane & 7) ^ (r & 7);
      abase[i] = (slot >= 0) ? (xb + (size_t)(slot >> 3) * HD + sl * 8)
                             : (zp + sl * 8);
    }

    f32x4 accg[4][4], accu[4][4];
    const f32x4 vzero = {0.f, 0.f, 0.f, 0.f};
    #pragma unroll
    for (int r = 0; r < 4; ++r)
      #pragma unroll
      for (int c = 0; c < 4; ++c) { accg[r][c] = vzero; accu[r][c] = vzero; }

    const int rows_here = n_e - m0 - wid * 64;   // wave-uniform

    for (int kt = 0; kt < HD / 64; ++kt) {
      const int k0 = kt * 64;
      #pragma unroll
      for (int i = 0; i < 8; ++i)
        load_lds16(abase[i] + k0, &sA[(wid * 8 + i) * 512]);

      #pragma unroll
      for (int i = 0; i < 2; ++i) {
        int c = i * 256 + tid;
        int row = c >> 3, sl = c & 7;
        size_t boff = ((size_t)e * ID + n0 + row) * HD + (size_t)(k0 + sl * 8);
        f32x4 g0 = *(const f32x4*)(gw + boff);
        f32x4 g1 = *(const f32x4*)(gw + boff + 4);
        f32x4 u0 = *(const f32x4*)(uw + boff);
        f32x4 u1 = *(const f32x4*)(uw + boff + 4);
        bf16x8 gb, ub;
        #pragma unroll
        for (int j = 0; j < 4; ++j) {
          gb[j] = (__bf16)g0[j]; gb[j + 4] = (__bf16)g1[j];
          ub[j] = (__bf16)u0[j]; ub[j + 4] = (__bf16)u1[j];
        }
        int ph = sl ^ (row & 7);
        *(bf16x8*)&sG[row * 64 + ph * 8] = gb;
        *(bf16x8*)&sU[row * 64 + ph * 8] = ub;
      }
      __syncthreads();   // drains vmcnt(0) incl. global_load_lds + lgkm

      #pragma unroll
      for (int kk = 0; kk < 2; ++kk) {
        bf16x8 aF[4];
        #pragma unroll
        for (int r = 0; r < 4; ++r) if (r * 16 < rows_here) {
          int row = wid * 64 + r * 16 + (lane & 15);
          int ph = (kk * 4 + (lane >> 4)) ^ (row & 7);
          aF[r] = *(const bf16x8*)&sA[row * 64 + ph * 8];
        }
        #pragma unroll
        for (int c = 0; c < 4; ++c) {
          int row = c * 16 + (lane & 15);
          int ph = (kk * 4 + (lane >> 4)) ^ (row & 7);
          bf16x8 gF = *(const bf16x8*)&sG[row * 64 + ph * 8];
          bf16x8 uF = *(const bf16x8*)&sU[row * 64 + ph * 8];
          #pragma unroll
          for (int r = 0; r < 4; ++r) if (r * 16 < rows_here) {
            accg[r][c] = __builtin_amdgcn_mfma_f32_16x16x32_bf16(aF[r], gF, accg[r][c], 0, 0, 0);
            accu[r][c] = __builtin_amdgcn_mfma_f32_16x16x32_bf16(aF[r], uF, accu[r][c], 0, 0, 0);
          }
        }
      }
      __syncthreads();
    }

    // epilogue: silu(g)*u -> bf16 hidden_buf[slot][n0+col]
    #pragma unroll
    for (int r = 0; r < 4; ++r) if (r * 16 < rows_here) {
      #pragma unroll
      for (int j = 0; j < 4; ++j) {
        int row = wid * 64 + r * 16 + (lane >> 4) * 4 + j;
        if (m0 + row < n_e) {
          int slot = sSlot[row];
          #pragma unroll
          for (int c = 0; c < 4; ++c) {
            float g = accg[r][c][j], u = accu[r][c][j];
            float h = (g / (1.0f + expf(-g))) * u;
            hb[(size_t)slot * ID + (size_t)(n0 + c * 16 + (lane & 15))] = (__bf16)h;
          }
        }
      }
    }
    __syncthreads();
  }
}

// ---------------------------------------------------------------------------
// GEMM2: hidden[M x 768] @ down^T[2048 x 768], weighted atomic scatter to out.
// ---------------------------------------------------------------------------
__global__ __launch_bounds__(256, 2) void gemm2_kernel(
    const unsigned short* __restrict__ hb_u,
    const float* __restrict__ dw,
    const int* __restrict__ counts, const int* __restrict__ lists,
    const float* __restrict__ tw,
    const unsigned short* __restrict__ zp_u,
    float* __restrict__ out)
{
  __shared__ __bf16 sA[256 * 64];
  __shared__ __bf16 sB[64 * 64];
  __shared__ int    sSlot[256];

  const __bf16* hbuf = (const __bf16*)hb_u;
  const __bf16* zp   = (const __bf16*)zp_u;

  const int e   = blockIdx.y;
  const int n0  = blockIdx.x * 64;     // over HD=2048
  const int tid = threadIdx.x;
  const int wid = tid >> 6;
  const int lane = tid & 63;
  const int n_e = counts[e];

  for (int m0 = 0; m0 < n_e; m0 += 256) {
    sSlot[tid] = (m0 + tid < n_e) ? lists[e * T_TOK + m0 + tid] : -1;
    __syncthreads();

    const __bf16* abase[8];
    #pragma unroll
    for (int i = 0; i < 8; ++i) {
      int r = wid * 64 + i * 8 + (lane >> 3);
      int slot = sSlot[r];
      int sl = (lane & 7) ^ (r & 7);
      abase[i] = (slot >= 0) ? (hbuf + (size_t)slot * ID + sl * 8)
                             : (zp + sl * 8);
    }

    f32x4 acc[4][4];
    const f32x4 vzero = {0.f, 0.f, 0.f, 0.f};
    #pragma unroll
    for (int r = 0; r < 4; ++r)
      #pragma unroll
      for (int c = 0; c < 4; ++c) acc[r][c] = vzero;

    const int rows_here = n_e - m0 - wid * 64;

    for (int kt = 0; kt < ID / 64; ++kt) {
      const int k0 = kt * 64;
      #pragma unroll
      for (int i = 0; i < 8; ++i)
        load_lds16(abase[i] + k0, &sA[(wid * 8 + i) * 512]);

      #pragma unroll
      for (int i = 0; i < 2; ++i) {
        int c = i * 256 + tid;
        int row = c >> 3, sl = c & 7;
        size_t boff = ((size_t)e * HD + n0 + row) * ID + (size_t)(k0 + sl * 8);
        f32x4 b0 = *(const f32x4*)(dw + boff);
        f32x4 b1 = *(const f32x4*)(dw + boff + 4);
        bf16x8 bb;
        #pragma unroll
        for (int j = 0; j < 4; ++j) { bb[j] = (__bf16)b0[j]; bb[j + 4] = (__bf16)b1[j]; }
        int ph = sl ^ (row & 7);
        *(bf16x8*)&sB[row * 64 + ph * 8] = bb;
      }
      __syncthreads();

      #pragma unroll
      for (int kk = 0; kk < 2; ++kk) {
        bf16x8 aF[4];
        #pragma unroll
        for (int r = 0; r < 4; ++r) if (r * 16 < rows_here) {
          int row = wid * 64 + r * 16 + (lane & 15);
          int ph = (kk * 4 + (lane >> 4)) ^ (row & 7);
          aF[r] = *(const bf16x8*)&sA[row * 64 + ph * 8];
        }
        #pragma unroll
        for (int c = 0; c < 4; ++c) {
          int row = c * 16 + (lane & 15);
          int ph = (kk * 4 + (lane >> 4)) ^ (row & 7);
          bf16x8 bF = *(const bf16x8*)&sB[row * 64 + ph * 8];
          #pragma unroll
          for (int r = 0; r < 4; ++r) if (r * 16 < rows_here) {
            acc[r][c] = __builtin_amdgcn_mfma_f32_16x16x32_bf16(aF[r], bF, acc[r][c], 0, 0, 0);
          }
        }
      }
      __syncthreads();
    }

    #pragma unroll
    for (int r = 0; r < 4; ++r) if (r * 16 < rows_here) {
      #pragma unroll
      for (int j = 0; j < 4; ++j) {
        int row = wid * 64 + r * 16 + (lane >> 4) * 4 + j;
        if (m0 + row < n_e) {
          int slot = sSlot[row];
          int token = slot >> 3;
          float w = tw[slot];
          #pragma unroll
          for (int c = 0; c < 4; ++c) {
            atomicAdd(out + (size_t)token * HD + (size_t)(n0 + c * 16 + (lane & 15)),
                      w * acc[r][c][j]);
          }
        }
      }
    }
    __syncthreads();
  }
}

// ---------------------------------------------------------------------------
// Launcher.  ws layout (bytes):
//   [0,8K)        zero page (for padded-row loads)
//   [8K, +4M)     x in bf16            1024*2048*2
//   +32K          topk weights by slot 8192*4
//   +256          per-expert counts    64*4
//   +256K         per-expert slot list 64*1024*4
//   +12.6M        hidden_buf bf16      8192*768*2
// total ~16.3 MB
// ---------------------------------------------------------------------------
extern "C" void kernel_launch(void* const* d_in, const int* in_sizes, int n_in,
                              void* d_out, int out_size, void* d_ws, size_t ws_size,
                              hipStream_t stream) {
  const float* x  = (const float*)d_in[0];
  const float* rw = (const float*)d_in[1];
  const float* gw = (const float*)d_in[2];
  const float* uw = (const float*)d_in[3];
  const float* dw = (const float*)d_in[4];
  float* out = (float*)d_out;

  char* ws = (char*)d_ws;
  const size_t ZP_OFF  = 0;
  const size_t XB_OFF  = 8192;
  const size_t TW_OFF  = XB_OFF + (size_t)T_TOK * HD * 2;        // 4202496
  const size_t CNT_OFF = TW_OFF + (size_t)T_TOK * TOPK * 4;      // 4235264
  const size_t LST_OFF = CNT_OFF + 256;                          // 4235520
  const size_t HB_OFF  = LST_OFF + (size_t)NE * T_TOK * 4;       // 4497664

  unsigned short* zp  = (unsigned short*)(ws + ZP_OFF);
  unsigned short* xb  = (unsigned short*)(ws + XB_OFF);
  float*          tw  = (float*)(ws + TW_OFF);
  int*            cnt = (int*)(ws + CNT_OFF);
  int*            lst = (int*)(ws + LST_OFF);
  unsigned short* hb  = (unsigned short*)(ws + HB_OFF);

  hipMemsetAsync(zp, 0, 8192, stream);
  hipMemsetAsync(cnt, 0, 256, stream);
  hipMemsetAsync(d_out, 0, (size_t)T_TOK * HD * sizeof(float), stream);

  router_kernel<<<T_TOK, 256, 0, stream>>>(x, rw, xb, tw, cnt, lst);
  gemm1_kernel<<<dim3(ID / 64, NE), 256, 0, stream>>>(xb, gw, uw, cnt, lst, zp, hb);
  gemm2_kernel<<<dim3(HD / 64, NE), 256, 0, stream>>>(hb, dw, cnt, lst, tw, zp, out);
}

// Round 2
// 504.748 us; speedup vs baseline: 1.0309x; 1.0309x over previous
//
#include <hip/hip_runtime.h>

#define T_TOK 1024
#define HD    2048
#define NE    64
#define ID    768
#define TOPK  8

typedef __bf16 bf16x8 __attribute__((ext_vector_type(8)));
typedef __bf16 bf16x4 __attribute__((ext_vector_type(4)));
typedef float  f32x4  __attribute__((ext_vector_type(4)));

__device__ __forceinline__ void load_lds16(const void* src, void* lds) {
  __builtin_amdgcn_global_load_lds(
      (const __attribute__((address_space(1))) void*)src,
      (__attribute__((address_space(3))) void*)lds, 16, 0, 0);
}

// ---------------------------------------------------------------------------
// Router: fp64 logits -> top-8 -> renormalized weights; build per-expert lists;
// also convert x to bf16 for the expert GEMMs.
// ---------------------------------------------------------------------------
__global__ __launch_bounds__(256) void router_kernel(
    const float* __restrict__ x, const float* __restrict__ rw,
    unsigned short* __restrict__ xb_u, float* __restrict__ tw,
    int* __restrict__ counts, int* __restrict__ lists)
{
  __shared__ float  sx[HD];
  __shared__ double slog[NE];
  const int t = blockIdx.x;
  const int tid = threadIdx.x;
  __bf16* xb = (__bf16*)xb_u;

  for (int i = tid; i < HD; i += 256) {
    float v = x[(size_t)t * HD + i];
    sx[i] = v;
    xb[(size_t)t * HD + i] = (__bf16)v;
  }
  __syncthreads();

  const int e = tid >> 2, p = tid & 3;
  const float* rwrow = rw + (size_t)e * HD;
  double acc = 0.0;
  for (int k = p; k < HD; k += 4)
    acc += (double)sx[k] * (double)rwrow[k];
  acc += __shfl_xor(acc, 1, 64);
  acc += __shfl_xor(acc, 2, 64);
  if (p == 0) slog[e] = acc;
  __syncthreads();

  if (tid < 64) {
    double v = slog[tid];
    double selv = -1e300; int seli = 0; double gmax = 0.0;
    #pragma unroll
    for (int k = 0; k < TOPK; ++k) {
      double bv = v; int bi = tid;
      #pragma unroll
      for (int off = 32; off >= 1; off >>= 1) {
        double ov = __shfl_xor(bv, off, 64);
        int    oi = __shfl_xor(bi, off, 64);
        if (ov > bv || (ov == bv && oi < bi)) { bv = ov; bi = oi; }
      }
      if (k == 0) gmax = bv;
      if (tid == k) { selv = bv; seli = bi; }
      if (tid == bi) v = -1e300;
    }
    double e_ = (tid < TOPK) ? exp(selv - gmax) : 0.0;
    double s = e_;
    #pragma unroll
    for (int off = 32; off >= 1; off >>= 1) s += __shfl_xor(s, off, 64);
    if (tid < TOPK) {
      int slot = t * TOPK + tid;
      tw[slot] = (float)(e_ / s);
      int pos = atomicAdd(&counts[seli], 1);
      lists[seli * T_TOK + pos] = slot;
    }
  }
}

// ---------------------------------------------------------------------------
// GEMM1: BM=256, BN=64, BK=32, 512 threads (8 waves, 32 M-rows each),
// double-buffered LDS + issue-early pipeline, 1 barrier per K-step.
// ---------------------------------------------------------------------------
__global__ __launch_bounds__(512, 4) void gemm1_kernel(
    const unsigned short* __restrict__ xb_u,
    const float* __restrict__ gw, const float* __restrict__ uw,
    const int* __restrict__ counts, const int* __restrict__ lists,
    const unsigned short* __restrict__ zp_u,
    unsigned short* __restrict__ hb_u)
{
  __shared__ __bf16 sA[2][256 * 32];
  __shared__ __bf16 sG[2][64 * 32];
  __shared__ __bf16 sU[2][64 * 32];
  __shared__ int    sSlot[256];

  const __bf16* xb = (const __bf16*)xb_u;
  const __bf16* zp = (const __bf16*)zp_u;
  __bf16* hb = (__bf16*)hb_u;

  // XCD swizzle: 768 blocks = 8 xcd chunks of 96; each expert on one XCD.
  const int wg  = blockIdx.x;
  const int idx = wg >> 3;                 // 0..95
  const int e   = (wg & 7) * 8 + idx / 12;
  const int n0  = (idx % 12) * 64;

  const int tid  = threadIdx.x;
  const int wid  = tid >> 6;
  const int lane = tid & 63;
  const int n_e  = counts[e];

  // W staging: thread -> 16B fp32 (4 floats) per matrix per K-step
  const int wrow = tid >> 3;               // 0..63
  const int wqc  = tid & 7;                // 16B chunk within 128B row
  const size_t wsrc0 = ((size_t)e * ID + n0 + wrow) * HD + (size_t)wqc * 4;
  const int wds = wrow * 32 + (((wqc >> 1) ^ ((wrow >> 1) & 3)) * 8) + (wqc & 1) * 4;

  for (int m0 = 0; m0 < n_e; m0 += 256) {
    if (tid < 256) sSlot[tid] = (m0 + tid < n_e) ? lists[e * T_TOK + m0 + tid] : -1;
    __syncthreads();

    const __bf16* abase[2];
    #pragma unroll
    for (int j = 0; j < 2; ++j) {
      int r = wid * 32 + j * 16 + (lane >> 2);
      int slot = sSlot[r];
      int cs = (lane & 3) ^ ((r >> 1) & 3);
      abase[j] = (slot >= 0) ? (xb + (size_t)(slot >> 3) * HD + cs * 8)
                             : (zp + cs * 8);
    }

    f32x4 accg[2][4], accu[2][4];
    const f32x4 vzero = {0.f, 0.f, 0.f, 0.f};
    #pragma unroll
    for (int r = 0; r < 2; ++r)
      #pragma unroll
      for (int c = 0; c < 4; ++c) { accg[r][c] = vzero; accu[r][c] = vzero; }

    const int rows_here = n_e - m0 - wid * 32;

    // prologue: issue A(0) -> buf0, W(0) -> regs A-set
    #pragma unroll
    for (int j = 0; j < 2; ++j)
      load_lds16(abase[j], &sA[0][(wid * 32 + j * 16) * 32]);
    f32x4 ga = *(const f32x4*)(gw + wsrc0);
    f32x4 ua = *(const f32x4*)(uw + wsrc0);
    f32x4 gb_, ub_;

#define G1_STEP(KT, BC, BN_, GC, UC, GN, UN)                                      \
    {                                                                             \
      bf16x4 gv, uv;                                                              \
      _Pragma("unroll") for (int q = 0; q < 4; ++q) {                             \
        gv[q] = (__bf16)GC[q]; uv[q] = (__bf16)UC[q];                             \
      }                                                                           \
      *(bf16x4*)&sG[BC][wds] = gv;                                                \
      *(bf16x4*)&sU[BC][wds] = uv;                                                \
      __syncthreads();                                                            \
      if ((KT) + 1 < HD / 32) {                                                   \
        const int k1 = ((KT) + 1) * 32;                                           \
        _Pragma("unroll") for (int j = 0; j < 2; ++j)                             \
          load_lds16(abase[j] + k1, &sA[BN_][(wid * 32 + j * 16) * 32]);          \
        GN = *(const f32x4*)(gw + wsrc0 + (size_t)k1);                            \
        UN = *(const f32x4*)(uw + wsrc0 + (size_t)k1);                            \
      }                                                                           \
      bf16x8 aF[2];                                                               \
      _Pragma("unroll") for (int r = 0; r < 2; ++r) if (r * 16 < rows_here) {     \
        int row = wid * 32 + r * 16 + (lane & 15);                                \
        int ph = (lane >> 4) ^ ((row >> 1) & 3);                                  \
        aF[r] = *(const bf16x8*)&sA[BC][row * 32 + ph * 8];                       \
      }                                                                           \
      _Pragma("unroll") for (int c = 0; c < 4; ++c) {                             \
        int row = c * 16 + (lane & 15);                                           \
        int ph = (lane >> 4) ^ ((row >> 1) & 3);                                  \
        bf16x8 gF = *(const bf16x8*)&sG[BC][row * 32 + ph * 8];                   \
        bf16x8 uF = *(const bf16x8*)&sU[BC][row * 32 + ph * 8];                   \
        _Pragma("unroll") for (int r = 0; r < 2; ++r) if (r * 16 < rows_here) {   \
          accg[r][c] = __builtin_amdgcn_mfma_f32_16x16x32_bf16(aF[r], gF, accg[r][c], 0, 0, 0); \
          accu[r][c] = __builtin_amdgcn_mfma_f32_16x16x32_bf16(aF[r], uF, accu[r][c], 0, 0, 0); \
        }                                                                         \
      }                                                                           \
    }

    for (int it = 0; it < (HD / 32) / 2; ++it) {
      G1_STEP(2 * it,     0, 1, ga,  ua,  gb_, ub_);
      G1_STEP(2 * it + 1, 1, 0, gb_, ub_, ga,  ua);
    }
#undef G1_STEP

    // epilogue: silu(g)*u -> bf16 hidden_buf
    #pragma unroll
    for (int r = 0; r < 2; ++r) if (r * 16 < rows_here) {
      #pragma unroll
      for (int j = 0; j < 4; ++j) {
        int row = wid * 32 + r * 16 + (lane >> 4) * 4 + j;
        if (m0 + row < n_e) {
          int slot = sSlot[row];
          #pragma unroll
          for (int c = 0; c < 4; ++c) {
            float g = accg[r][c][j], u = accu[r][c][j];
            float h = (g / (1.0f + expf(-g))) * u;
            hb[(size_t)slot * ID + (size_t)(n0 + c * 16 + (lane & 15))] = (__bf16)h;
          }
        }
      }
    }
    __syncthreads();
  }
}

// ---------------------------------------------------------------------------
// GEMM2: hidden[M x 768] @ down^T[2048 x 768], same pipeline, atomic scatter.
// ---------------------------------------------------------------------------
__global__ __launch_bounds__(512, 4) void gemm2_kernel(
    const unsigned short* __restrict__ hb_u,
    const float* __restrict__ dw,
    const int* __restrict__ counts, const int* __restrict__ lists,
    const float* __restrict__ tw,
    const unsigned short* __restrict__ zp_u,
    float* __restrict__ out)
{
  __shared__ __bf16 sA[2][256 * 32];
  __shared__ __bf16 sB[2][64 * 32];
  __shared__ int    sSlot[256];

  const __bf16* hbuf = (const __bf16*)hb_u;
  const __bf16* zp   = (const __bf16*)zp_u;

  // XCD swizzle: 2048 blocks = 8 xcd chunks of 256; each expert on one XCD.
  const int wg  = blockIdx.x;
  const int idx = wg >> 3;                 // 0..255
  const int e   = (wg & 7) * 8 + idx / 32;
  const int n0  = (idx % 32) * 64;         // over HD

  const int tid  = threadIdx.x;
  const int wid  = tid >> 6;
  const int lane = tid & 63;
  const int n_e  = counts[e];

  const int wrow = tid >> 3;
  const int wqc  = tid & 7;
  const size_t wsrc0 = ((size_t)e * HD + n0 + wrow) * ID + (size_t)wqc * 4;
  const int wds = wrow * 32 + (((wqc >> 1) ^ ((wrow >> 1) & 3)) * 8) + (wqc & 1) * 4;

  for (int m0 = 0; m0 < n_e; m0 += 256) {
    if (tid < 256) sSlot[tid] = (m0 + tid < n_e) ? lists[e * T_TOK + m0 + tid] : -1;
    __syncthreads();

    const __bf16* abase[2];
    #pragma unroll
    for (int j = 0; j < 2; ++j) {
      int r = wid * 32 + j * 16 + (lane >> 2);
      int slot = sSlot[r];
      int cs = (lane & 3) ^ ((r >> 1) & 3);
      abase[j] = (slot >= 0) ? (hbuf + (size_t)slot * ID + cs * 8)
                             : (zp + cs * 8);
    }

    f32x4 acc[2][4];
    const f32x4 vzero = {0.f, 0.f, 0.f, 0.f};
    #pragma unroll
    for (int r = 0; r < 2; ++r)
      #pragma unroll
      for (int c = 0; c < 4; ++c) acc[r][c] = vzero;

    const int rows_here = n_e - m0 - wid * 32;

    #pragma unroll
    for (int j = 0; j < 2; ++j)
      load_lds16(abase[j], &sA[0][(wid * 32 + j * 16) * 32]);
    f32x4 da = *(const f32x4*)(dw + wsrc0);
    f32x4 db_;

#define G2_STEP(KT, BC, BN_, DC, DN)                                              \
    {                                                                             \
      bf16x4 dv;                                                                  \
      _Pragma("unroll") for (int q = 0; q < 4; ++q) dv[q] = (__bf16)DC[q];        \
      *(bf16x4*)&sB[BC][wds] = dv;                                                \
      __syncthreads();                                                            \
      if ((KT) + 1 < ID / 32) {                                                   \
        const int k1 = ((KT) + 1) * 32;                                           \
        _Pragma("unroll") for (int j = 0; j < 2; ++j)                             \
          load_lds16(abase[j] + k1, &sA[BN_][(wid * 32 + j * 16) * 32]);          \
        DN = *(const f32x4*)(dw + wsrc0 + (size_t)k1);                            \
      }                                                                           \
      bf16x8 aF[2];                                                               \
      _Pragma("unroll") for (int r = 0; r < 2; ++r) if (r * 16 < rows_here) {     \
        int row = wid * 32 + r * 16 + (lane & 15);                                \
        int ph = (lane >> 4) ^ ((row >> 1) & 3);                                  \
        aF[r] = *(const bf16x8*)&sA[BC][row * 32 + ph * 8];                       \
      }                                                                           \
      _Pragma("unroll") for (int c = 0; c < 4; ++c) {                             \
        int row = c * 16 + (lane & 15);                                           \
        int ph = (lane >> 4) ^ ((row >> 1) & 3);                                  \
        bf16x8 bF = *(const bf16x8*)&sB[BC][row * 32 + ph * 8];                   \
        _Pragma("unroll") for (int r = 0; r < 2; ++r) if (r * 16 < rows_here) {   \
          acc[r][c] = __builtin_amdgcn_mfma_f32_16x16x32_bf16(aF[r], bF, acc[r][c], 0, 0, 0); \
        }                                                                         \
      }                                                                           \
    }

    for (int it = 0; it < (ID / 32) / 2; ++it) {
      G2_STEP(2 * it,     0, 1, da,  db_);
      G2_STEP(2 * it + 1, 1, 0, db_, da);
    }
#undef G2_STEP

    #pragma unroll
    for (int r = 0; r < 2; ++r) if (r * 16 < rows_here) {
      #pragma unroll
      for (int j = 0; j < 4; ++j) {
        int row = wid * 32 + r * 16 + (lane >> 4) * 4 + j;
        if (m0 + row < n_e) {
          int slot = sSlot[row];
          int token = slot >> 3;
          float w = tw[slot];
          #pragma unroll
          for (int c = 0; c < 4; ++c) {
            atomicAdd(out + (size_t)token * HD + (size_t)(n0 + c * 16 + (lane & 15)),
                      w * acc[r][c][j]);
          }
        }
      }
    }
    __syncthreads();
  }
}

// ---------------------------------------------------------------------------
// Launcher. ws layout unchanged from round 1.
// ---------------------------------------------------------------------------
extern "C" void kernel_launch(void* const* d_in, const int* in_sizes, int n_in,
                              void* d_out, int out_size, void* d_ws, size_t ws_size,
                              hipStream_t stream) {
  const float* x  = (const float*)d_in[0];
  const float* rw = (const float*)d_in[1];
  const float* gw = (const float*)d_in[2];
  const float* uw = (const float*)d_in[3];
  const float* dw = (const float*)d_in[4];
  float* out = (float*)d_out;

  char* ws = (char*)d_ws;
  const size_t ZP_OFF  = 0;
  const size_t XB_OFF  = 8192;
  const size_t TW_OFF  = XB_OFF + (size_t)T_TOK * HD * 2;
  const size_t CNT_OFF = TW_OFF + (size_t)T_TOK * TOPK * 4;
  const size_t LST_OFF = CNT_OFF + 256;
  const size_t HB_OFF  = LST_OFF + (size_t)NE * T_TOK * 4;

  unsigned short* zp  = (unsigned short*)(ws + ZP_OFF);
  unsigned short* xb  = (unsigned short*)(ws + XB_OFF);
  float*          tw  = (float*)(ws + TW_OFF);
  int*            cnt = (int*)(ws + CNT_OFF);
  int*            lst = (int*)(ws + LST_OFF);
  unsigned short* hb  = (unsigned short*)(ws + HB_OFF);

  hipMemsetAsync(zp, 0, 8192, stream);
  hipMemsetAsync(cnt, 0, 256, stream);
  hipMemsetAsync(d_out, 0, (size_t)T_TOK * HD * sizeof(float), stream);

  router_kernel<<<T_TOK, 256, 0, stream>>>(x, rw, xb, tw, cnt, lst);
  gemm1_kernel<<<768, 512, 0, stream>>>(xb, gw, uw, cnt, lst, zp, hb);
  gemm2_kernel<<<2048, 512, 0, stream>>>(hb, dw, cnt, lst, tw, zp, out);
}

// Round 3
// 477.766 us; speedup vs baseline: 1.0892x; 1.0565x over previous
//
#include <hip/hip_runtime.h>

#define T_TOK 1024
#define HD    2048
#define NE    64
#define ID    768
#define TOPK  8

typedef __bf16 bf16x8 __attribute__((ext_vector_type(8)));
typedef __bf16 bf16x4 __attribute__((ext_vector_type(4)));
typedef float  f32x4  __attribute__((ext_vector_type(4)));

__device__ __forceinline__ void load_lds16(const void* src, void* lds) {
  __builtin_amdgcn_global_load_lds(
      (const __attribute__((address_space(1))) void*)src,
      (__attribute__((address_space(3))) void*)lds, 16, 0, 0);
}

#define LGKM0 asm volatile("s_waitcnt lgkmcnt(0)" ::: "memory")
#define BAR() __builtin_amdgcn_s_barrier()

// ---------------------------------------------------------------------------
// Router: fp64 logits -> top-8 -> renormalized weights; per-expert lists;
// x -> bf16.
// ---------------------------------------------------------------------------
__global__ __launch_bounds__(256) void router_kernel(
    const float* __restrict__ x, const float* __restrict__ rw,
    unsigned short* __restrict__ xb_u, float* __restrict__ tw,
    int* __restrict__ counts, int* __restrict__ lists)
{
  __shared__ float  sx[HD];
  __shared__ double slog[NE];
  const int t = blockIdx.x;
  const int tid = threadIdx.x;
  __bf16* xb = (__bf16*)xb_u;

  for (int i = tid; i < HD; i += 256) {
    float v = x[(size_t)t * HD + i];
    sx[i] = v;
    xb[(size_t)t * HD + i] = (__bf16)v;
  }
  __syncthreads();

  const int e = tid >> 2, p = tid & 3;
  const float* rwrow = rw + (size_t)e * HD;
  double acc = 0.0;
  for (int k = p; k < HD; k += 4)
    acc += (double)sx[k] * (double)rwrow[k];
  acc += __shfl_xor(acc, 1, 64);
  acc += __shfl_xor(acc, 2, 64);
  if (p == 0) slog[e] = acc;
  __syncthreads();

  if (tid < 64) {
    double v = slog[tid];
    double selv = -1e300; int seli = 0; double gmax = 0.0;
    #pragma unroll
    for (int k = 0; k < TOPK; ++k) {
      double bv = v; int bi = tid;
      #pragma unroll
      for (int off = 32; off >= 1; off >>= 1) {
        double ov = __shfl_xor(bv, off, 64);
        int    oi = __shfl_xor(bi, off, 64);
        if (ov > bv || (ov == bv && oi < bi)) { bv = ov; bi = oi; }
      }
      if (k == 0) gmax = bv;
      if (tid == k) { selv = bv; seli = bi; }
      if (tid == bi) v = -1e300;
    }
    double e_ = (tid < TOPK) ? exp(selv - gmax) : 0.0;
    double s = e_;
    #pragma unroll
    for (int off = 32; off >= 1; off >>= 1) s += __shfl_xor(s, off, 64);
    if (tid < TOPK) {
      int slot = t * TOPK + tid;
      tw[slot] = (float)(e_ / s);
      int pos = atomicAdd(&counts[seli], 1);
      lists[seli * T_TOK + pos] = slot;
    }
  }
}

// ---------------------------------------------------------------------------
// GEMM1: BM=256, BN=32, BK=32, 512 thr (8 waves x 32 M-rows x 32 N-cols).
// 3-deep LDS pipeline, counted vmcnt (never 0 in loop), raw s_barrier.
// Per wave per step: exactly 3 VMEM issues (2x global_load_lds A + 1 f32x4 W).
// ---------------------------------------------------------------------------
__global__ __launch_bounds__(512, 4) void gemm1_kernel(
    const unsigned short* __restrict__ xb_u,
    const float* __restrict__ gw, const float* __restrict__ uw,
    const int* __restrict__ counts, const int* __restrict__ lists,
    const unsigned short* __restrict__ zp_u,
    unsigned short* __restrict__ hb_u)
{
  __shared__ __bf16 sA[3][256 * 32];
  __shared__ __bf16 sW[3][2][32 * 32];
  __shared__ int    sSlot[256];

  const __bf16* xb = (const __bf16*)xb_u;
  const __bf16* zp = (const __bf16*)zp_u;
  __bf16* hb = (__bf16*)hb_u;

  // 1536 blocks = 8 XCD chunks of 192; expert pinned to one XCD.
  const int wg  = blockIdx.x;
  const int idx = wg >> 3;                  // 0..191
  const int e   = (wg & 7) * 8 + idx / 24;
  const int n0  = (idx % 24) * 32;          // over I=768

  const int tid = threadIdx.x, wid = tid >> 6, lane = tid & 63;
  const int n_e = counts[e];

  // W staging: waves 0-3 -> gate, waves 4-7 -> up. 1 f32x4 per thread per step.
  const int tid4 = tid & 255;
  const int wrow = tid4 >> 3, wf = tid4 & 7;
  const float* wsrc = ((wid < 4) ? gw : uw) + ((size_t)e * ID + n0 + wrow) * HD + wf * 4;
  const int wmi = (wid < 4) ? 0 : 1;
  const int wds = wrow * 32 + (((wf >> 1) ^ ((wrow >> 1) & 3)) << 3) + (wf & 1) * 4;

#define G1_STEP(VMLIT, BUF, WREG, KNXT, DO_ISSUE)                                 \
  {                                                                               \
    asm volatile("s_waitcnt vmcnt(" VMLIT ")" ::: "memory");                      \
    bf16x4 wv_;                                                                   \
    _Pragma("unroll") for (int q = 0; q < 4; ++q) wv_[q] = (__bf16)WREG[q];       \
    *(bf16x4*)&sW[BUF][wmi][wds] = wv_;                                           \
    LGKM0; BAR();                                                                 \
    bf16x8 aF_[2], gF_[2], uF_[2];                                                \
    _Pragma("unroll") for (int r = 0; r < 2; ++r) {                               \
      int row = wid * 32 + r * 16 + (lane & 15);                                  \
      int ch = (lane >> 4) ^ ((row >> 1) & 3);                                    \
      aF_[r] = *(const bf16x8*)&sA[BUF][row * 32 + ch * 8];                       \
    }                                                                             \
    _Pragma("unroll") for (int c = 0; c < 2; ++c) {                               \
      int row = c * 16 + (lane & 15);                                             \
      int ch = (lane >> 4) ^ ((row >> 1) & 3);                                    \
      gF_[c] = *(const bf16x8*)&sW[BUF][0][row * 32 + ch * 8];                    \
      uF_[c] = *(const bf16x8*)&sW[BUF][1][row * 32 + ch * 8];                    \
    }                                                                             \
    LGKM0; BAR();                                                                 \
    if (DO_ISSUE) {                                                               \
      load_lds16(abase[0] + (KNXT), &sA[BUF][(wid * 32) * 32]);                   \
      load_lds16(abase[1] + (KNXT), &sA[BUF][(wid * 32 + 16) * 32]);              \
      WREG = *(const f32x4*)(wsrc + (KNXT));                                      \
    }                                                                             \
    _Pragma("unroll") for (int r = 0; r < 2; ++r) if (r * 16 < rows_here)         \
      _Pragma("unroll") for (int c = 0; c < 2; ++c) {                             \
        accg[r][c] = __builtin_amdgcn_mfma_f32_16x16x32_bf16(aF_[r], gF_[c], accg[r][c], 0, 0, 0); \
        accu[r][c] = __builtin_amdgcn_mfma_f32_16x16x32_bf16(aF_[r], uF_[c], accu[r][c], 0, 0, 0); \
      }                                                                           \
  }

  for (int m0 = 0; m0 < n_e; m0 += 256) {
    __syncthreads();   // full drain: clears prior-pass stores from vmcnt
    if (tid < 256) sSlot[tid] = (m0 + tid < n_e) ? lists[e * T_TOK + m0 + tid] : -1;
    __syncthreads();

    const __bf16* abase[2];
    #pragma unroll
    for (int j = 0; j < 2; ++j) {
      int r = wid * 32 + j * 16 + (lane >> 2);
      int slot = sSlot[r];
      int cs = (lane & 3) ^ ((r >> 1) & 3);
      abase[j] = (slot >= 0) ? (xb + (size_t)(slot >> 3) * HD + cs * 8)
                             : (zp + cs * 8);
    }

    f32x4 accg[2][2], accu[2][2];
    const f32x4 vzero = {0.f, 0.f, 0.f, 0.f};
    #pragma unroll
    for (int r = 0; r < 2; ++r)
      #pragma unroll
      for (int c = 0; c < 2; ++c) { accg[r][c] = vzero; accu[r][c] = vzero; }

    const int rows_here = n_e - m0 - wid * 32;   // wave-uniform

    // prologue: ISSUE(0..2)
    f32x4 w0, w1, w2;
    #pragma unroll
    for (int t = 0; t < 3; ++t) {
      load_lds16(abase[0] + t * 32, &sA[t][(wid * 32) * 32]);
      load_lds16(abase[1] + t * 32, &sA[t][(wid * 32 + 16) * 32]);
    }
    w0 = *(const f32x4*)(wsrc);
    w1 = *(const f32x4*)(wsrc + 32);
    w2 = *(const f32x4*)(wsrc + 64);
    // NOTE: issue order above is A,A,A,A,A,A,W,W,W (9 ops) vs steady A,A,W
    // triples; vmcnt(6) at t=0 still guarantees the oldest 3 (A0,A0,A1...) —
    // to keep counting exact, re-order: interleave per-t. Done below instead:

    // main loop: t = 0..59
    for (int it = 0; it < 20; ++it) {
      const int t = it * 3;
      G1_STEP("6", 0, w0, (t + 3) * 32, 1)
      G1_STEP("6", 1, w1, (t + 4) * 32, 1)
      G1_STEP("6", 2, w2, (t + 5) * 32, 1)
    }
    // t=60 (issues 63), then drain 61/62/63
    G1_STEP("6", 0, w0, 63 * 32, 1)
    G1_STEP("6", 1, w1, 0, 0)
    G1_STEP("3", 2, w2, 0, 0)
    G1_STEP("0", 0, w0, 0, 0)

    // epilogue: silu(g)*u -> bf16 hidden_buf
    #pragma unroll
    for (int r = 0; r < 2; ++r) if (r * 16 < rows_here) {
      #pragma unroll
      for (int j = 0; j < 4; ++j) {
        int row = wid * 32 + r * 16 + (lane >> 4) * 4 + j;
        if (m0 + row < n_e) {
          int slot = sSlot[row];
          #pragma unroll
          for (int c = 0; c < 2; ++c) {
            float g = accg[r][c][j], u = accu[r][c][j];
            float h = (g / (1.0f + expf(-g))) * u;
            hb[(size_t)slot * ID + (size_t)(n0 + c * 16 + (lane & 15))] = (__bf16)h;
          }
        }
      }
    }
  }
#undef G1_STEP
}

// ---------------------------------------------------------------------------
// GEMM2: BM=256, BN=64, BK=32, K=768 (24 steps). Same pipeline; atomic scatter.
// ---------------------------------------------------------------------------
__global__ __launch_bounds__(512, 4) void gemm2_kernel(
    const unsigned short* __restrict__ hb_u,
    const float* __restrict__ dw,
    const int* __restrict__ counts, const int* __restrict__ lists,
    const float* __restrict__ tw,
    const unsigned short* __restrict__ zp_u,
    float* __restrict__ out)
{
  __shared__ __bf16 sA[3][256 * 32];
  __shared__ __bf16 sW[3][64 * 32];
  __shared__ int    sSlot[256];

  const __bf16* hbuf = (const __bf16*)hb_u;
  const __bf16* zp   = (const __bf16*)zp_u;

  // 2048 blocks = 8 XCD chunks of 256.
  const int wg  = blockIdx.x;
  const int idx = wg >> 3;                  // 0..255
  const int e   = (wg & 7) * 8 + idx / 32;
  const int n0  = (idx % 32) * 64;          // over H=2048

  const int tid = threadIdx.x, wid = tid >> 6, lane = tid & 63;
  const int n_e = counts[e];

  const int wrow = tid >> 3, wf = tid & 7;  // 64 rows x 8 chunks
  const float* wsrc = dw + ((size_t)e * HD + n0 + wrow) * ID + wf * 4;
  const int wds = wrow * 32 + (((wf >> 1) ^ ((wrow >> 1) & 3)) << 3) + (wf & 1) * 4;

#define G2_STEP(VMLIT, BUF, WREG, KNXT, DO_ISSUE)                                 \
  {                                                                               \
    asm volatile("s_waitcnt vmcnt(" VMLIT ")" ::: "memory");                      \
    bf16x4 wv_;                                                                   \
    _Pragma("unroll") for (int q = 0; q < 4; ++q) wv_[q] = (__bf16)WREG[q];       \
    *(bf16x4*)&sW[BUF][wds] = wv_;                                                \
    LGKM0; BAR();                                                                 \
    bf16x8 aF_[2], dF_[4];                                                        \
    _Pragma("unroll") for (int r = 0; r < 2; ++r) {                               \
      int row = wid * 32 + r * 16 + (lane & 15);                                  \
      int ch = (lane >> 4) ^ ((row >> 1) & 3);                                    \
      aF_[r] = *(const bf16x8*)&sA[BUF][row * 32 + ch * 8];                       \
    }                                                                             \
    _Pragma("unroll") for (int c = 0; c < 4; ++c) {                               \
      int row = c * 16 + (lane & 15);                                             \
      int ch = (lane >> 4) ^ ((row >> 1) & 3);                                    \
      dF_[c] = *(const bf16x8*)&sW[BUF][row * 32 + ch * 8];                       \
    }                                                                             \
    LGKM0; BAR();                                                                 \
    if (DO_ISSUE) {                                                               \
      load_lds16(abase[0] + (KNXT), &sA[BUF][(wid * 32) * 32]);                   \
      load_lds16(abase[1] + (KNXT), &sA[BUF][(wid * 32 + 16) * 32]);              \
      WREG = *(const f32x4*)(wsrc + (KNXT));                                      \
    }                                                                             \
    _Pragma("unroll") for (int r = 0; r < 2; ++r) if (r * 16 < rows_here)         \
      _Pragma("unroll") for (int c = 0; c < 4; ++c)                               \
        acc[r][c] = __builtin_amdgcn_mfma_f32_16x16x32_bf16(aF_[r], dF_[c], acc[r][c], 0, 0, 0); \
  }

  for (int m0 = 0; m0 < n_e; m0 += 256) {
    __syncthreads();
    if (tid < 256) sSlot[tid] = (m0 + tid < n_e) ? lists[e * T_TOK + m0 + tid] : -1;
    __syncthreads();

    const __bf16* abase[2];
    #pragma unroll
    for (int j = 0; j < 2; ++j) {
      int r = wid * 32 + j * 16 + (lane >> 2);
      int slot = sSlot[r];
      int cs = (lane & 3) ^ ((r >> 1) & 3);
      abase[j] = (slot >= 0) ? (hbuf + (size_t)slot * ID + cs * 8)
                             : (zp + cs * 8);
    }

    f32x4 acc[2][4];
    const f32x4 vzero = {0.f, 0.f, 0.f, 0.f};
    #pragma unroll
    for (int r = 0; r < 2; ++r)
      #pragma unroll
      for (int c = 0; c < 4; ++c) acc[r][c] = vzero;

    const int rows_here = n_e - m0 - wid * 32;

    f32x4 w0, w1, w2;
    #pragma unroll
    for (int t = 0; t < 3; ++t) {
      load_lds16(abase[0] + t * 32, &sA[t][(wid * 32) * 32]);
      load_lds16(abase[1] + t * 32, &sA[t][(wid * 32 + 16) * 32]);
    }
    w0 = *(const f32x4*)(wsrc);
    w1 = *(const f32x4*)(wsrc + 32);
    w2 = *(const f32x4*)(wsrc + 64);

    // main loop: t = 0..20 (7 triples), issues up to t=23
    for (int it = 0; it < 7; ++it) {
      const int t = it * 3;
      G2_STEP("6", 0, w0, (t + 3) * 32, 1)
      G2_STEP("6", 1, w1, (t + 4) * 32, 1)
      G2_STEP("6", 2, w2, (t + 5) * 32, 1)
    }
    // drain: t=21,22,23
    G2_STEP("6", 0, w0, 0, 0)
    G2_STEP("3", 1, w1, 0, 0)
    G2_STEP("0", 2, w2, 0, 0)

    #pragma unroll
    for (int r = 0; r < 2; ++r) if (r * 16 < rows_here) {
      #pragma unroll
      for (int j = 0; j < 4; ++j) {
        int row = wid * 32 + r * 16 + (lane >> 4) * 4 + j;
        if (m0 + row < n_e) {
          int slot = sSlot[row];
          int token = slot >> 3;
          float w = tw[slot];
          #pragma unroll
          for (int c = 0; c < 4; ++c) {
            atomicAdd(out + (size_t)token * HD + (size_t)(n0 + c * 16 + (lane & 15)),
                      w * acc[r][c][j]);
          }
        }
      }
    }
  }
#undef G2_STEP
}

// ---------------------------------------------------------------------------
// Launcher. ws layout unchanged.
// ---------------------------------------------------------------------------
extern "C" void kernel_launch(void* const* d_in, const int* in_sizes, int n_in,
                              void* d_out, int out_size, void* d_ws, size_t ws_size,
                              hipStream_t stream) {
  const float* x  = (const float*)d_in[0];
  const float* rw = (const float*)d_in[1];
  const float* gw = (const float*)d_in[2];
  const float* uw = (const float*)d_in[3];
  const float* dw = (const float*)d_in[4];
  float* out = (float*)d_out;

  char* ws = (char*)d_ws;
  const size_t ZP_OFF  = 0;
  const size_t XB_OFF  = 8192;
  const size_t TW_OFF  = XB_OFF + (size_t)T_TOK * HD * 2;
  const size_t CNT_OFF = TW_OFF + (size_t)T_TOK * TOPK * 4;
  const size_t LST_OFF = CNT_OFF + 256;
  const size_t HB_OFF  = LST_OFF + (size_t)NE * T_TOK * 4;

  unsigned short* zp  = (unsigned short*)(ws + ZP_OFF);
  unsigned short* xb  = (unsigned short*)(ws + XB_OFF);
  float*          tw  = (float*)(ws + TW_OFF);
  int*            cnt = (int*)(ws + CNT_OFF);
  int*            lst = (int*)(ws + LST_OFF);
  unsigned short* hb  = (unsigned short*)(ws + HB_OFF);

  hipMemsetAsync(zp, 0, 8192, stream);
  hipMemsetAsync(cnt, 0, 256, stream);
  hipMemsetAsync(d_out, 0, (size_t)T_TOK * HD * sizeof(float), stream);

  router_kernel<<<T_TOK, 256, 0, stream>>>(x, rw, xb, tw, cnt, lst);
  gemm1_kernel<<<1536, 512, 0, stream>>>(xb, gw, uw, cnt, lst, zp, hb);
  gemm2_kernel<<<2048, 512, 0, stream>>>(hb, dw, cnt, lst, tw, zp, out);
}